// Round 6
// baseline (85.972 us; speedup 1.0000x reference)
//
#include <hip/hip_runtime.h>
#include <hip/hip_bf16.h>

// ---- problem constants ----
#define NBATCH   16
#define SIGLEN   240000
#define FRAMES   1197                 // (240000-800)/200 + 1
#define M_TOTAL  (NBATCH * FRAMES)    // 19152
#define K_TOTAL  800
#define NBINS    401
#define NOUT     (2 * NBINS)          // 802, interleaved re/im
#define FSTEP    200

// ---- GEMM tiling ----
#define BM 128
#define BN 128
#define BK 32
#define NT (K_TOTAL / BK)             // 25 K-steps
#define NTILES_N 7                    // ceil(802/128)
#define NTILES_M 150                  // ceil(19152/128)
#define NWG      (NTILES_M * NTILES_N) // 1050
#define N_PAD    (NTILES_N * BN)      // 896

#define SIG_ELEMS ((size_t)NBATCH * SIGLEN)           // 3,840,000 bf16
#define B_WS_ELEMS ((size_t)N_PAD * K_TOTAL)          // 716,800 bf16
#define WS_NEEDED  ((SIG_ELEMS + B_WS_ELEMS) * 2)     // ~9.1 MB

#define PREP_SIG_BLOCKS 1875          // SIG_ELEMS/8/256
#define PREP_B_BLOCKS   350           // N_PAD*100/256

typedef float  f32x4  __attribute__((ext_vector_type(4)));
typedef __bf16 bf16x8 __attribute__((ext_vector_type(8)));

static __device__ __forceinline__ unsigned f2bf_pair(float lo, float hi) {
    // RNE f32->bf16, packed pair
    union { float f; unsigned u; } a, b;
    a.f = lo; b.f = hi;
    unsigned ua = (a.u + 0x7fffu + ((a.u >> 16) & 1u)) >> 16;
    unsigned ub = (b.u + 0x7fffu + ((b.u >> 16) & 1u)) >> 16;
    return ua | (ub << 16);
}

// ============================================================================
// fused prep: blocks [0,1875) convert signal f32->bf16 (8 elems/thread);
// blocks [1875,2225) build windowed interleaved-DFT bf16 rows (padded)
// ============================================================================
__global__ __launch_bounds__(256) void prep_all(
    const float* __restrict__ sig, const float* __restrict__ wnd,
    const float* __restrict__ dcos, const float* __restrict__ dsin,
    ushort* __restrict__ sbf, ushort* __restrict__ B)
{
    const int blk = blockIdx.x;
    if (blk < PREP_SIG_BLOCKS) {
        size_t i8 = ((size_t)blk * 256 + threadIdx.x) * 8;
        const float4 s0 = *(const float4*)(sig + i8);
        const float4 s1 = *(const float4*)(sig + i8 + 4);
        uint4 p;
        p.x = f2bf_pair(s0.x, s0.y);
        p.y = f2bf_pair(s0.z, s0.w);
        p.z = f2bf_pair(s1.x, s1.y);
        p.w = f2bf_pair(s1.z, s1.w);
        *(uint4*)(sbf + i8) = p;
    } else {
        int idx = (blk - PREP_SIG_BLOCKS) * 256 + threadIdx.x;  // < N_PAD*100
        int j  = idx / 100;
        int c8 = (idx - j * 100) * 8;
        uint4 p;
        if (j < NOUT) {
            const float* src = ((j & 1) ? dsin : dcos) + (size_t)(j >> 1) * K_TOTAL + c8;
            const float4 s0 = *(const float4*)(src);
            const float4 s1 = *(const float4*)(src + 4);
            const float4 w0 = *(const float4*)(wnd + c8);
            const float4 w1 = *(const float4*)(wnd + c8 + 4);
            p.x = f2bf_pair(s0.x * w0.x, s0.y * w0.y);
            p.y = f2bf_pair(s0.z * w0.z, s0.w * w0.w);
            p.z = f2bf_pair(s1.x * w1.x, s1.y * w1.y);
            p.w = f2bf_pair(s1.z * w1.z, s1.w * w1.w);
        } else {
            p = make_uint4(0u, 0u, 0u, 0u);
        }
        *(uint4*)(B + (size_t)j * K_TOTAL + c8) = p;
    }
}

// ============================================================================
// GEMM: C[19152 x 802] = frames[M,800] * Bw^T[802,800]
// Register-direct: NO LDS, NO barriers. Each lane loads its MFMA fragments
// straight from global (L2-resident; 4 lanes share each 64B line). Two named
// fragment sets ping-pong (static indexing, rule #20); waves free-run, TLP
// hides L2 latency. A gathered from bf16 signal (frames = contiguous slices).
// ============================================================================
__global__ __launch_bounds__(256) void stft_gemm_reg(
    const ushort* __restrict__ sigbf, const ushort* __restrict__ Bw,
    float* __restrict__ out)
{
    const int tid = threadIdx.x;

    // bijective XCD swizzle (m204): nwg=1050, q=131, r=2
    const int orig = blockIdx.x;
    const int xcd  = orig & 7;
    const int lid  = orig >> 3;
    const int bid  = (xcd < 2 ? xcd * 132 : 264 + (xcd - 2) * 131) + lid;

    const int mt = bid / NTILES_N;
    const int nt = bid - mt * NTILES_N;
    const int m0 = mt * BM;
    const int j0 = nt * BN;

    const int wave = tid >> 6;
    const int lane = tid & 63;
    const int wm   = wave >> 1;
    const int wn   = wave & 1;
    const int lr   = lane & 15;
    const int lg   = lane >> 4;

    // per-lane fragment base pointers (k=0), 16B-aligned
    const ushort* aP[4];
    const ushort* bP[4];
    #pragma unroll
    for (int i = 0; i < 4; ++i) {
        int row = m0 + wm * 64 + i * 16 + lr;
        if (row >= M_TOTAL) row = M_TOTAL - 1;      // pad rows: dup, not stored
        int bb = row / FRAMES, ff = row - bb * FRAMES;
        aP[i] = sigbf + (size_t)bb * SIGLEN + ff * FSTEP + lg * 8;
        bP[i] = Bw + (size_t)(j0 + wn * 64 + i * 16 + lr) * K_TOTAL + lg * 8;
    }

    f32x4 acc[4][4];
    #pragma unroll
    for (int i = 0; i < 4; ++i)
        #pragma unroll
        for (int jj = 0; jj < 4; ++jj)
            acc[i][jj] = (f32x4){0.f, 0.f, 0.f, 0.f};

#define LOADF(A_, B_, kofs) do {                                   \
        _Pragma("unroll")                                          \
        for (int i = 0; i < 4; ++i) {                              \
            A_[i] = *(const bf16x8*)(aP[i] + (kofs));              \
            B_[i] = *(const bf16x8*)(bP[i] + (kofs));              \
        }                                                          \
    } while (0)

#define MM(A_, B_) do {                                            \
        __builtin_amdgcn_s_setprio(1);                             \
        _Pragma("unroll")                                          \
        for (int i = 0; i < 4; ++i)                                \
            _Pragma("unroll")                                      \
            for (int jj = 0; jj < 4; ++jj)                         \
                acc[i][jj] = __builtin_amdgcn_mfma_f32_16x16x32_bf16( \
                    A_[i], B_[jj], acc[i][jj], 0, 0, 0);           \
        __builtin_amdgcn_s_setprio(0);                             \
    } while (0)

    bf16x8 aX[4], bX[4], aY[4], bY[4];
    LOADF(aX, bX, 0);

    // NT=25 (odd): 12 double-iterations + final MM. Loads for step t+1 issue
    // before MFMAs of step t -> compiler pipelines; no barriers anywhere.
    #pragma unroll 1
    for (int t = 0; t < NT - 1; t += 2) {
        LOADF(aY, bY, (t + 1) * BK);
        MM(aX, bX);
        LOADF(aX, bX, (t + 2) * BK);
        MM(aY, bY);
    }
    MM(aX, bX);   // k-step 24

#undef LOADF
#undef MM

    // epilogue: C/D layout col=lane&15, row=4*(lane>>4)+reg
    const int mb = m0 + wm * 64;
    const int jb = j0 + wn * 64;
    #pragma unroll
    for (int i = 0; i < 4; ++i) {
        #pragma unroll
        for (int jj = 0; jj < 4; ++jj) {
            int col = jb + jj * 16 + lr;
            if (col >= NOUT) continue;
            #pragma unroll
            for (int r = 0; r < 4; ++r) {
                int row = mb + i * 16 + lg * 4 + r;
                if (row < M_TOTAL)
                    out[(size_t)row * NOUT + col] = acc[i][jj][r];
            }
        }
    }
}

// ============================================================================
// fallback (no workspace): in-kernel gather+window+convert
// ============================================================================
#define LDSS 40
__global__ __launch_bounds__(256) void stft_gemm_fb(
    const float* __restrict__ sig, const float* __restrict__ wnd,
    const float* __restrict__ dcos, const float* __restrict__ dsin,
    float* __restrict__ out)
{
    __shared__ ushort As[BM * LDSS];
    __shared__ ushort Bs[BN * LDSS];
    __shared__ int rowBase[BM];

    const int tid = threadIdx.x;
    const int bid = blockIdx.x;
    const int mt  = bid / NTILES_N;
    const int nt  = bid - mt * NTILES_N;
    const int m0  = mt * BM;
    const int j0  = nt * BN;

    if (tid < BM) {
        int m = m0 + tid;
        int v = -1;
        if (m < M_TOTAL) {
            int b  = m / FRAMES;
            int fl = m - b * FRAMES;
            v = b * SIGLEN + fl * FSTEP;
        }
        rowBase[tid] = v;
    }

    const int rS = tid >> 1;
    const int hS = tid & 1;

    const float* bRow = nullptr;
    {
        int j = j0 + rS;
        if (j < NOUT) {
            const float* srcm = (j & 1) ? dsin : dcos;
            bRow = srcm + (size_t)(j >> 1) * K_TOTAL;
        }
    }

    const int lane = tid & 63;
    const int wave = tid >> 6;
    const int wm   = wave >> 1;
    const int wn   = wave & 1;
    const int lr   = lane & 15;
    const int lg   = lane >> 4;

    f32x4 acc[4][4];
    #pragma unroll
    for (int i = 0; i < 4; ++i)
        #pragma unroll
        for (int jj = 0; jj < 4; ++jj)
            acc[i][jj] = (f32x4){0.f, 0.f, 0.f, 0.f};

    __syncthreads();

    for (int k0 = 0; k0 < K_TOTAL; k0 += BK) {
        {
            int base = rowBase[rS];
            float4 f0, f1, f2, f3;
            if (base >= 0) {
                const float4* sp = (const float4*)(sig + base + k0 + hS * 16);
                f0 = sp[0]; f1 = sp[1]; f2 = sp[2]; f3 = sp[3];
            } else {
                f0 = make_float4(0.f,0.f,0.f,0.f); f1 = f0; f2 = f0; f3 = f0;
            }
            const float4* wp = (const float4*)(wnd + k0 + hS * 16);
            float4 w0 = wp[0], w1 = wp[1], w2 = wp[2], w3 = wp[3];
            uint4 p0, p1;
            p0.x = f2bf_pair(f0.x * w0.x, f0.y * w0.y);
            p0.y = f2bf_pair(f0.z * w0.z, f0.w * w0.w);
            p0.z = f2bf_pair(f1.x * w1.x, f1.y * w1.y);
            p0.w = f2bf_pair(f1.z * w1.z, f1.w * w1.w);
            p1.x = f2bf_pair(f2.x * w2.x, f2.y * w2.y);
            p1.y = f2bf_pair(f2.z * w2.z, f2.w * w2.w);
            p1.z = f2bf_pair(f3.x * w3.x, f3.y * w3.y);
            p1.w = f2bf_pair(f3.z * w3.z, f3.w * w3.w);
            uint4* dst = (uint4*)&As[rS * LDSS + hS * 16];
            dst[0] = p0; dst[1] = p1;
        }
        {
            uint4 p0, p1;
            if (bRow) {
                const float4* sp = (const float4*)(bRow + k0 + hS * 16);
                float4 f0 = sp[0], f1 = sp[1], f2 = sp[2], f3 = sp[3];
                p0.x = f2bf_pair(f0.x, f0.y);
                p0.y = f2bf_pair(f0.z, f0.w);
                p0.z = f2bf_pair(f1.x, f1.y);
                p0.w = f2bf_pair(f1.z, f1.w);
                p1.x = f2bf_pair(f2.x, f2.y);
                p1.y = f2bf_pair(f2.z, f2.w);
                p1.z = f2bf_pair(f3.x, f3.y);
                p1.w = f2bf_pair(f3.z, f3.w);
            } else {
                p0 = make_uint4(0u,0u,0u,0u); p1 = p0;
            }
            uint4* dst = (uint4*)&Bs[rS * LDSS + hS * 16];
            dst[0] = p0; dst[1] = p1;
        }
        __syncthreads();

        bf16x8 a[4], b[4];
        #pragma unroll
        for (int i = 0; i < 4; ++i)
            a[i] = *(const bf16x8*)&As[(wm * 64 + i * 16 + lr) * LDSS + lg * 8];
        #pragma unroll
        for (int i = 0; i < 4; ++i)
            b[i] = *(const bf16x8*)&Bs[(wn * 64 + i * 16 + lr) * LDSS + lg * 8];
        #pragma unroll
        for (int i = 0; i < 4; ++i)
            #pragma unroll
            for (int jj = 0; jj < 4; ++jj)
                acc[i][jj] = __builtin_amdgcn_mfma_f32_16x16x32_bf16(a[i], b[jj], acc[i][jj], 0, 0, 0);

        __syncthreads();
    }

    const int mb = m0 + wm * 64;
    const int jb = j0 + wn * 64;
    #pragma unroll
    for (int i = 0; i < 4; ++i) {
        #pragma unroll
        for (int jj = 0; jj < 4; ++jj) {
            int col = jb + jj * 16 + lr;
            if (col >= NOUT) continue;
            #pragma unroll
            for (int r = 0; r < 4; ++r) {
                int row = mb + i * 16 + lg * 4 + r;
                if (row < M_TOTAL)
                    out[(size_t)row * NOUT + col] = acc[i][jj][r];
            }
        }
    }
}

extern "C" void kernel_launch(void* const* d_in, const int* in_sizes, int n_in,
                              void* d_out, int out_size, void* d_ws, size_t ws_size,
                              hipStream_t stream) {
    const float* sig  = (const float*)d_in[0];
    const float* wnd  = (const float*)d_in[1];
    const float* dcos = (const float*)d_in[2];
    const float* dsin = (const float*)d_in[3];
    float* out = (float*)d_out;

    if (ws_size >= WS_NEEDED && d_ws != nullptr) {
        ushort* sbf = (ushort*)d_ws;
        ushort* Bws = sbf + SIG_ELEMS;
        prep_all<<<dim3(PREP_SIG_BLOCKS + PREP_B_BLOCKS), dim3(256), 0, stream>>>(
            sig, wnd, dcos, dsin, sbf, Bws);
        stft_gemm_reg<<<dim3(NWG), dim3(256), 0, stream>>>(sbf, Bws, out);
    } else {
        stft_gemm_fb<<<dim3(NWG), dim3(256), 0, stream>>>(sig, wnd, dcos, dsin, out);
    }
}

// Round 7
// 78.228 us; speedup vs baseline: 1.0990x; 1.0990x over previous
//
#include <hip/hip_runtime.h>
#include <hip/hip_bf16.h>

// ---- problem constants ----
#define NBATCH   16
#define SIGLEN   240000
#define FRAMES   1197                 // (240000-800)/200 + 1
#define M_TOTAL  (NBATCH * FRAMES)    // 19152
#define K_TOTAL  800
#define NBINS    401
#define NOUT     (2 * NBINS)          // 802, interleaved re/im
#define FSTEP    200

#define BK 32
#define NT (K_TOTAL / BK)             // 25 K-steps

// ---- new GEMM geometry: B-panel-resident-in-LDS ----
#define GBN   64                      // N per block (B panel rows)
#define GMB   512                     // M rows per block (8 waves x 64)
#define GNT   13                      // ceil(802/64)
#define GMT   38                      // ceil(19152/512)
#define GNWG  (GNT * GMT)             // 494
#define BSTR  808                     // LDS row stride (bf16): 808%... -> uniform banks
#define N_PAD (GNT * GBN)             // 832

#define SIG_ELEMS  ((size_t)NBATCH * SIGLEN)          // 3,840,000 bf16
#define B_WS_ELEMS ((size_t)N_PAD * K_TOTAL)          // 665,600 bf16
#define WS_NEEDED  ((SIG_ELEMS + B_WS_ELEMS) * 2)     // ~9.0 MB

#define PREP_SIG_BLOCKS 1875          // SIG_ELEMS/8/256
#define PREP_B_BLOCKS   325           // N_PAD*100/256

typedef float  f32x4  __attribute__((ext_vector_type(4)));
typedef __bf16 bf16x8 __attribute__((ext_vector_type(8)));

static __device__ __forceinline__ unsigned f2bf_pair(float lo, float hi) {
    // RNE f32->bf16, packed pair
    union { float f; unsigned u; } a, b;
    a.f = lo; b.f = hi;
    unsigned ua = (a.u + 0x7fffu + ((a.u >> 16) & 1u)) >> 16;
    unsigned ub = (b.u + 0x7fffu + ((b.u >> 16) & 1u)) >> 16;
    return ua | (ub << 16);
}

// ============================================================================
// fused prep: blocks [0,1875) convert signal f32->bf16 (8 elems/thread);
// blocks [1875,2200) build windowed interleaved-DFT bf16 rows (padded to 832)
// ============================================================================
__global__ __launch_bounds__(256) void prep_all(
    const float* __restrict__ sig, const float* __restrict__ wnd,
    const float* __restrict__ dcos, const float* __restrict__ dsin,
    ushort* __restrict__ sbf, ushort* __restrict__ B)
{
    const int blk = blockIdx.x;
    if (blk < PREP_SIG_BLOCKS) {
        size_t i8 = ((size_t)blk * 256 + threadIdx.x) * 8;
        const float4 s0 = *(const float4*)(sig + i8);
        const float4 s1 = *(const float4*)(sig + i8 + 4);
        uint4 p;
        p.x = f2bf_pair(s0.x, s0.y);
        p.y = f2bf_pair(s0.z, s0.w);
        p.z = f2bf_pair(s1.x, s1.y);
        p.w = f2bf_pair(s1.z, s1.w);
        *(uint4*)(sbf + i8) = p;
    } else {
        int idx = (blk - PREP_SIG_BLOCKS) * 256 + threadIdx.x;  // < N_PAD*100
        int j  = idx / 100;
        int c8 = (idx - j * 100) * 8;
        uint4 p;
        if (j < NOUT) {
            const float* src = ((j & 1) ? dsin : dcos) + (size_t)(j >> 1) * K_TOTAL + c8;
            const float4 s0 = *(const float4*)(src);
            const float4 s1 = *(const float4*)(src + 4);
            const float4 w0 = *(const float4*)(wnd + c8);
            const float4 w1 = *(const float4*)(wnd + c8 + 4);
            p.x = f2bf_pair(s0.x * w0.x, s0.y * w0.y);
            p.y = f2bf_pair(s0.z * w0.z, s0.w * w0.w);
            p.z = f2bf_pair(s1.x * w1.x, s1.y * w1.y);
            p.w = f2bf_pair(s1.z * w1.z, s1.w * w1.w);
        } else {
            p = make_uint4(0u, 0u, 0u, 0u);
        }
        *(uint4*)(B + (size_t)j * K_TOTAL + c8) = p;
    }
}

// ============================================================================
// GEMM: C[19152 x 802] = frames[M,800] * Bw^T[802,800]
// B panel (64 x 800) staged in LDS ONCE per block (stride 808: uniform
// 8-lanes/bank on ds_read_b128 = conflict-free). 8 waves x 64 rows each; A
// fragments per-lane direct from bf16 signal (L2-resident, frames overlap).
// K-loop: NO barriers, NO LDS writes; depth-2 (X/Y/Z) register pipeline.
// ============================================================================
__global__ __launch_bounds__(512, 2) void stft_gemm_breg(
    const ushort* __restrict__ sigbf, const ushort* __restrict__ Bw,
    float* __restrict__ out)
{
    __shared__ ushort Bs[GBN * BSTR];   // 103,424 B

    const int tid = threadIdx.x;

    // bijective XCD swizzle (m204): nwg=494, q=61, r=6
    const int orig = blockIdx.x;
    const int xcd  = orig & 7;
    const int lid  = orig >> 3;
    const int bid  = (xcd < 6 ? xcd * 62 : 372 + (xcd - 6) * 61) + lid;

    // consecutive bids share the same B panel (N-tile) for L2 locality
    const int ntile = bid / GMT;
    const int mblk  = bid - ntile * GMT;
    const int j0    = ntile * GBN;
    const int m0    = mblk * GMB;

    const int wave = tid >> 6;
    const int lane = tid & 63;
    const int lr   = lane & 15;
    const int lg   = lane >> 4;

    // ---- stage B panel: 64 rows x 800 cols -> LDS [64][808] ----
    {
        #pragma unroll
        for (int r = 0; r < 12; ++r) {
            int c   = tid + 512 * r;            // chunk id < 6400
            int row = c / 100;
            int col = (c - row * 100) * 8;
            *(uint4*)&Bs[row * BSTR + col] =
                *(const uint4*)(Bw + (size_t)(j0 + row) * K_TOTAL + col);
        }
        if (tid < 256) {
            int c   = tid + 6144;
            int row = c / 100;
            int col = (c - row * 100) * 8;
            *(uint4*)&Bs[row * BSTR + col] =
                *(const uint4*)(Bw + (size_t)(j0 + row) * K_TOTAL + col);
        }
    }

    // ---- per-lane A fragment pointers (k=0) ----
    const int mrow = m0 + wave * 64;
    const ushort* aP[4];
    #pragma unroll
    for (int i = 0; i < 4; ++i) {
        int row = mrow + i * 16 + lr;
        if (row >= M_TOTAL) row = M_TOTAL - 1;   // pad rows: dup, not stored
        int bb = row / FRAMES, ff = row - bb * FRAMES;
        aP[i] = sigbf + (size_t)bb * SIGLEN + ff * FSTEP + lg * 8;
    }
    const int bBase = lr * BSTR + lg * 8;        // + jj*16*BSTR + k

    f32x4 acc[4][4];
    #pragma unroll
    for (int i = 0; i < 4; ++i)
        #pragma unroll
        for (int jj = 0; jj < 4; ++jj)
            acc[i][jj] = (f32x4){0.f, 0.f, 0.f, 0.f};

#define LOADA(A_, step) do {                                       \
        const int kofs_ = (step) * BK;                             \
        _Pragma("unroll")                                          \
        for (int i = 0; i < 4; ++i)                                \
            A_[i] = *(const bf16x8*)(aP[i] + kofs_);               \
    } while (0)

#define LOADB(B_, step) do {                                       \
        const int kofs_ = (step) * BK;                             \
        _Pragma("unroll")                                          \
        for (int jj = 0; jj < 4; ++jj)                             \
            B_[jj] = *(const bf16x8*)&Bs[jj * (16 * BSTR) + bBase + kofs_]; \
    } while (0)

#define MM(A_, B_) do {                                            \
        __builtin_amdgcn_s_setprio(1);                             \
        _Pragma("unroll")                                          \
        for (int i = 0; i < 4; ++i)                                \
            _Pragma("unroll")                                      \
            for (int jj = 0; jj < 4; ++jj)                         \
                acc[i][jj] = __builtin_amdgcn_mfma_f32_16x16x32_bf16( \
                    A_[i], B_[jj], acc[i][jj], 0, 0, 0);           \
        __builtin_amdgcn_s_setprio(0);                             \
    } while (0)

    bf16x8 aX[4], bX[4], aY[4], bY[4], aZ[4], bZ[4];

    // A loads are independent of LDS -> issue before the barrier
    LOADA(aX, 0);
    LOADA(aY, 1);

    __syncthreads();   // B panel ready; only barrier in the kernel

    LOADB(bX, 0);
    LOADB(bY, 1);

    // 25 K-steps: 8 iterations x 3 steps + final. Loads lead use by 2 MMs.
    #pragma unroll 1
    for (int t = 0; t + 3 <= NT - 1; t += 3) {
        const int s3 = (t + 3 < NT) ? t + 3 : NT - 1;
        const int s4 = (t + 4 < NT) ? t + 4 : NT - 1;
        LOADA(aZ, t + 2); LOADB(bZ, t + 2);
        MM(aX, bX);
        LOADA(aX, s3);    LOADB(bX, s3);
        MM(aY, bY);
        LOADA(aY, s4);    LOADB(bY, s4);
        MM(aZ, bZ);
    }
    MM(aX, bX);   // k-step 24

#undef LOADA
#undef LOADB
#undef MM

    // epilogue: C/D layout col=lane&15, row=4*(lane>>4)+reg
    #pragma unroll
    for (int i = 0; i < 4; ++i) {
        #pragma unroll
        for (int jj = 0; jj < 4; ++jj) {
            int col = j0 + jj * 16 + lr;
            if (col >= NOUT) continue;
            #pragma unroll
            for (int r = 0; r < 4; ++r) {
                int row = mrow + i * 16 + lg * 4 + r;
                if (row < M_TOTAL)
                    out[(size_t)row * NOUT + col] = acc[i][jj][r];
            }
        }
    }
}

// ============================================================================
// fallback (no workspace): in-kernel gather+window+convert (R1 structure)
// ============================================================================
#define BM 128
#define BN 128
#define NTILES_N 7
#define NTILES_M 150
#define NWG (NTILES_M * NTILES_N)
#define LDSS 40
__global__ __launch_bounds__(256) void stft_gemm_fb(
    const float* __restrict__ sig, const float* __restrict__ wnd,
    const float* __restrict__ dcos, const float* __restrict__ dsin,
    float* __restrict__ out)
{
    __shared__ ushort As[BM * LDSS];
    __shared__ ushort Bs[BN * LDSS];
    __shared__ int rowBase[BM];

    const int tid = threadIdx.x;
    const int bid = blockIdx.x;
    const int mt  = bid / NTILES_N;
    const int nt  = bid - mt * NTILES_N;
    const int m0  = mt * BM;
    const int j0  = nt * BN;

    if (tid < BM) {
        int m = m0 + tid;
        int v = -1;
        if (m < M_TOTAL) {
            int b  = m / FRAMES;
            int fl = m - b * FRAMES;
            v = b * SIGLEN + fl * FSTEP;
        }
        rowBase[tid] = v;
    }

    const int rS = tid >> 1;
    const int hS = tid & 1;

    const float* bRow = nullptr;
    {
        int j = j0 + rS;
        if (j < NOUT) {
            const float* srcm = (j & 1) ? dsin : dcos;
            bRow = srcm + (size_t)(j >> 1) * K_TOTAL;
        }
    }

    const int lane = tid & 63;
    const int wave = tid >> 6;
    const int wm   = wave >> 1;
    const int wn   = wave & 1;
    const int lr   = lane & 15;
    const int lg   = lane >> 4;

    f32x4 acc[4][4];
    #pragma unroll
    for (int i = 0; i < 4; ++i)
        #pragma unroll
        for (int jj = 0; jj < 4; ++jj)
            acc[i][jj] = (f32x4){0.f, 0.f, 0.f, 0.f};

    __syncthreads();

    for (int k0 = 0; k0 < K_TOTAL; k0 += BK) {
        {
            int base = rowBase[rS];
            float4 f0, f1, f2, f3;
            if (base >= 0) {
                const float4* sp = (const float4*)(sig + base + k0 + hS * 16);
                f0 = sp[0]; f1 = sp[1]; f2 = sp[2]; f3 = sp[3];
            } else {
                f0 = make_float4(0.f,0.f,0.f,0.f); f1 = f0; f2 = f0; f3 = f0;
            }
            const float4* wp = (const float4*)(wnd + k0 + hS * 16);
            float4 w0 = wp[0], w1 = wp[1], w2 = wp[2], w3 = wp[3];
            uint4 p0, p1;
            p0.x = f2bf_pair(f0.x * w0.x, f0.y * w0.y);
            p0.y = f2bf_pair(f0.z * w0.z, f0.w * w0.w);
            p0.z = f2bf_pair(f1.x * w1.x, f1.y * w1.y);
            p0.w = f2bf_pair(f1.z * w1.z, f1.w * w1.w);
            p1.x = f2bf_pair(f2.x * w2.x, f2.y * w2.y);
            p1.y = f2bf_pair(f2.z * w2.z, f2.w * w2.w);
            p1.z = f2bf_pair(f3.x * w3.x, f3.y * w3.y);
            p1.w = f2bf_pair(f3.z * w3.z, f3.w * w3.w);
            uint4* dst = (uint4*)&As[rS * LDSS + hS * 16];
            dst[0] = p0; dst[1] = p1;
        }
        {
            uint4 p0, p1;
            if (bRow) {
                const float4* sp = (const float4*)(bRow + k0 + hS * 16);
                float4 f0 = sp[0], f1 = sp[1], f2 = sp[2], f3 = sp[3];
                p0.x = f2bf_pair(f0.x, f0.y);
                p0.y = f2bf_pair(f0.z, f0.w);
                p0.z = f2bf_pair(f1.x, f1.y);
                p0.w = f2bf_pair(f1.z, f1.w);
                p1.x = f2bf_pair(f2.x, f2.y);
                p1.y = f2bf_pair(f2.z, f2.w);
                p1.z = f2bf_pair(f3.x, f3.y);
                p1.w = f2bf_pair(f3.z, f3.w);
            } else {
                p0 = make_uint4(0u,0u,0u,0u); p1 = p0;
            }
            uint4* dst = (uint4*)&Bs[rS * LDSS + hS * 16];
            dst[0] = p0; dst[1] = p1;
        }
        __syncthreads();

        bf16x8 a[4], b[4];
        #pragma unroll
        for (int i = 0; i < 4; ++i)
            a[i] = *(const bf16x8*)&As[(wm * 64 + i * 16 + lr) * LDSS + lg * 8];
        #pragma unroll
        for (int i = 0; i < 4; ++i)
            b[i] = *(const bf16x8*)&Bs[(wn * 64 + i * 16 + lr) * LDSS + lg * 8];
        #pragma unroll
        for (int i = 0; i < 4; ++i)
            #pragma unroll
            for (int jj = 0; jj < 4; ++jj)
                acc[i][jj] = __builtin_amdgcn_mfma_f32_16x16x32_bf16(a[i], b[jj], acc[i][jj], 0, 0, 0);

        __syncthreads();
    }

    const int mb = m0 + wm * 64;
    const int jb = j0 + wn * 64;
    #pragma unroll
    for (int i = 0; i < 4; ++i) {
        #pragma unroll
        for (int jj = 0; jj < 4; ++jj) {
            int col = jb + jj * 16 + lr;
            if (col >= NOUT) continue;
            #pragma unroll
            for (int r = 0; r < 4; ++r) {
                int row = mb + i * 16 + lg * 4 + r;
                if (row < M_TOTAL)
                    out[(size_t)row * NOUT + col] = acc[i][jj][r];
            }
        }
    }
}

extern "C" void kernel_launch(void* const* d_in, const int* in_sizes, int n_in,
                              void* d_out, int out_size, void* d_ws, size_t ws_size,
                              hipStream_t stream) {
    const float* sig  = (const float*)d_in[0];
    const float* wnd  = (const float*)d_in[1];
    const float* dcos = (const float*)d_in[2];
    const float* dsin = (const float*)d_in[3];
    float* out = (float*)d_out;

    if (ws_size >= WS_NEEDED && d_ws != nullptr) {
        ushort* sbf = (ushort*)d_ws;
        ushort* Bws = sbf + SIG_ELEMS;
        prep_all<<<dim3(PREP_SIG_BLOCKS + PREP_B_BLOCKS), dim3(256), 0, stream>>>(
            sig, wnd, dcos, dsin, sbf, Bws);
        stft_gemm_breg<<<dim3(GNWG), dim3(512), 0, stream>>>(sbf, Bws, out);
    } else {
        stft_gemm_fb<<<dim3(NWG), dim3(256), 0, stream>>>(sig, wnd, dcos, dsin, out);
    }
}

// Round 8
// 59.879 us; speedup vs baseline: 1.4358x; 1.3064x over previous
//
#include <hip/hip_runtime.h>
#include <hip/hip_bf16.h>

// ---- problem constants ----
#define NBATCH   16
#define SIGLEN   240000
#define FRAMES   1197                 // (240000-800)/200 + 1
#define M_TOTAL  (NBATCH * FRAMES)    // 19152
#define K_TOTAL  800
#define NBINS    401
#define NOUT     (2 * NBINS)          // 802, interleaved re/im
#define FSTEP    200

// ---- GEMM geometry: full-K B-panel resident in LDS, barrier-free K-loop ----
#define KPAD  832                     // K padded to 26*32 (B cols 800..831 zero)
#define NTK   26                      // K-steps of 32
#define GBN   64                      // N cols per block (B panel rows)
#define GMB   1024                    // M rows per block (8 waves x 128)
#define GNT   13                      // ceil(802/64)
#define GMT   19                      // ceil(19152/1024)
#define GNWG  (GNT * GMT)             // 247 blocks -> 1/CU, single shot
#define BSTR  840                     // LDS row stride bf16: 420 dw, %32=4 -> uniform banks

#define SIG_ELEMS  ((size_t)NBATCH * SIGLEN)          // 3,840,000 bf16
#define B_WS_ELEMS ((size_t)(GNT * GBN) * KPAD)       // 832*832 = 692,224 bf16
#define WS_NEEDED  ((SIG_ELEMS + B_WS_ELEMS) * 2)     // ~9.07 MB

#define PREP_SIG_BLOCKS 1875          // SIG_ELEMS/8/256
#define PREP_B_BLOCKS   338           // 832 rows * 104 chunks / 256

typedef float  f32x4  __attribute__((ext_vector_type(4)));
typedef __bf16 bf16x8 __attribute__((ext_vector_type(8)));

static __device__ __forceinline__ unsigned f2bf_pair(float lo, float hi) {
    // RNE f32->bf16, packed pair
    union { float f; unsigned u; } a, b;
    a.f = lo; b.f = hi;
    unsigned ua = (a.u + 0x7fffu + ((a.u >> 16) & 1u)) >> 16;
    unsigned ub = (b.u + 0x7fffu + ((b.u >> 16) & 1u)) >> 16;
    return ua | (ub << 16);
}

// ============================================================================
// fused prep: blocks [0,1875) convert signal f32->bf16 (8 elems/thread);
// blocks [1875,2213) build windowed interleaved-DFT bf16 rows, K-padded to 832
// row j (= output column j): j even -> w[n]*dft_cos[j/2][n], j odd -> sin
// ============================================================================
__global__ __launch_bounds__(256) void prep_all(
    const float* __restrict__ sig, const float* __restrict__ wnd,
    const float* __restrict__ dcos, const float* __restrict__ dsin,
    ushort* __restrict__ sbf, ushort* __restrict__ B)
{
    const int blk = blockIdx.x;
    if (blk < PREP_SIG_BLOCKS) {
        size_t i8 = ((size_t)blk * 256 + threadIdx.x) * 8;
        const float4 s0 = *(const float4*)(sig + i8);
        const float4 s1 = *(const float4*)(sig + i8 + 4);
        uint4 p;
        p.x = f2bf_pair(s0.x, s0.y);
        p.y = f2bf_pair(s0.z, s0.w);
        p.z = f2bf_pair(s1.x, s1.y);
        p.w = f2bf_pair(s1.z, s1.w);
        *(uint4*)(sbf + i8) = p;
    } else {
        int idx = (blk - PREP_SIG_BLOCKS) * 256 + threadIdx.x;  // < 832*104
        int j  = idx / 104;
        int c8 = (idx - j * 104) * 8;
        uint4 p;
        if (j < NOUT && c8 < K_TOTAL) {
            const float* src = ((j & 1) ? dsin : dcos) + (size_t)(j >> 1) * K_TOTAL + c8;
            const float4 s0 = *(const float4*)(src);
            const float4 s1 = *(const float4*)(src + 4);
            const float4 w0 = *(const float4*)(wnd + c8);
            const float4 w1 = *(const float4*)(wnd + c8 + 4);
            p.x = f2bf_pair(s0.x * w0.x, s0.y * w0.y);
            p.y = f2bf_pair(s0.z * w0.z, s0.w * w0.w);
            p.z = f2bf_pair(s1.x * w1.x, s1.y * w1.y);
            p.w = f2bf_pair(s1.z * w1.z, s1.w * w1.w);
        } else {
            p = make_uint4(0u, 0u, 0u, 0u);   // K-pad cols + N-pad rows
        }
        *(uint4*)(B + (size_t)j * KPAD + c8) = p;
    }
}

// ============================================================================
// GEMM: C[19152 x 802] = frames[M,800] * Bw^T[802,800(+pad)]
// 247 blocks (one/CU, no tail). Block stages its 64x832 B panel to LDS once
// (stride 840 -> uniform 8-accesses/bank on ds_read_b128). 8 waves, each owns
// 128x64 output (acc 8x4). A fragments per-lane direct from bf16 signal
// (L2-resident via XCD-chunked, ntile-fast grid order). K-loop: 26 steps,
// NO barriers, NO LDS writes; A/B register ping-pong, loads lead use by 2 MMs.
// ============================================================================
__global__ __launch_bounds__(512, 2) void stft_gemm_bp(
    const ushort* __restrict__ sigbf, const ushort* __restrict__ Bw,
    float* __restrict__ out)
{
    __shared__ ushort Bs[GBN * BSTR];   // 107,520 B -> 1 block/CU

    const int tid  = threadIdx.x;

    // XCD-chunked bijective swizzle (m204): nwg=247, q=30, r=7.
    // lbid consecutive within an XCD; ntile varies fastest -> each XCD's ~31
    // concurrent blocks share a ~1.2MB signal stripe + 1.4MB B => L2-resident.
    const int orig = blockIdx.x;
    const int xcd  = orig & 7;
    const int idx  = orig >> 3;
    const int lbid = (xcd < 7 ? xcd * 31 : 217 + (xcd - 7) * 30) + idx;

    const int ntile = lbid % GNT;
    const int mblk  = lbid / GNT;
    const int j0    = ntile * GBN;
    const int m0    = mblk * GMB;

    const int wave = tid >> 6;
    const int lane = tid & 63;
    const int lr   = lane & 15;
    const int lg   = lane >> 4;
    const int mrow = m0 + wave * 128;

    // per-lane A fragment offsets (8 rows); 32-bit so base pointer stays SGPR
    unsigned aOfs[8];
    #pragma unroll
    for (int i = 0; i < 8; ++i) {
        int row = mrow + i * 16 + lr;
        if (row >= M_TOTAL) row = M_TOTAL - 1;   // pad rows: dup, never stored
        int bb = row / FRAMES, ff = row - bb * FRAMES;
        aOfs[i] = (unsigned)(bb * SIGLEN + ff * FSTEP + lg * 8);
    }

    f32x4 acc[8][4];
    #pragma unroll
    for (int i = 0; i < 8; ++i)
        #pragma unroll
        for (int jj = 0; jj < 4; ++jj)
            acc[i][jj] = (f32x4){0.f, 0.f, 0.f, 0.f};

#define LOADA(A_, step) do {                                        \
        const int kofs_ = (step) * 32;                              \
        _Pragma("unroll")                                           \
        for (int i = 0; i < 8; ++i)                                 \
            A_[i] = *(const bf16x8*)(sigbf + aOfs[i] + kofs_);      \
    } while (0)

#define LOADB(B_, step) do {                                        \
        const int kofs_ = (step) * 32;                              \
        _Pragma("unroll")                                           \
        for (int jj = 0; jj < 4; ++jj)                              \
            B_[jj] = *(const bf16x8*)&Bs[jj * (16 * BSTR) + lr * BSTR + lg * 8 + kofs_]; \
    } while (0)

#define MM(A_, B_) do {                                             \
        _Pragma("unroll")                                           \
        for (int i = 0; i < 8; ++i)                                 \
            _Pragma("unroll")                                       \
            for (int jj = 0; jj < 4; ++jj)                          \
                acc[i][jj] = __builtin_amdgcn_mfma_f32_16x16x32_bf16( \
                    A_[i], B_[jj], acc[i][jj], 0, 0, 0);            \
    } while (0)

    bf16x8 aX[8], aY[8], bX[4], bY[4];

    // A prefetch (independent of LDS) before staging
    LOADA(aX, 0);
    LOADA(aY, 1);

    // ---- stage B panel: 64 rows x 832 cols -> LDS [64][840] ----
    // 6656 uint4 chunks = 512 threads x 13, exact
    #pragma unroll
    for (int it = 0; it < 13; ++it) {
        int c   = tid + 512 * it;
        int row = c / 104;
        int col = (c - row * 104) * 8;
        *(uint4*)&Bs[row * BSTR + col] =
            *(const uint4*)(Bw + (size_t)(j0 + row) * KPAD + col);
    }
    __syncthreads();   // only barrier in the kernel

    LOADB(bX, 0);
    LOADB(bY, 1);

    // 26 K-steps: 12 double-iterations + 2 tail MMs; loads lead use by 2 MMs
    #pragma unroll 1
    for (int t = 0; t < NTK - 2; t += 2) {
        MM(aX, bX);
        LOADA(aX, t + 2);
        LOADB(bX, t + 2);
        MM(aY, bY);
        LOADA(aY, t + 3);
        LOADB(bY, t + 3);
    }
    MM(aX, bX);   // step 24
    MM(aY, bY);   // step 25

#undef LOADA
#undef LOADB
#undef MM

    // epilogue: C/D layout col=lane&15, row=4*(lane>>4)+reg
    #pragma unroll
    for (int i = 0; i < 8; ++i) {
        #pragma unroll
        for (int jj = 0; jj < 4; ++jj) {
            int col = j0 + jj * 16 + lr;
            if (col >= NOUT) continue;
            #pragma unroll
            for (int r = 0; r < 4; ++r) {
                int row = mrow + i * 16 + lg * 4 + r;
                if (row < M_TOTAL)
                    out[(size_t)row * NOUT + col] = acc[i][jj][r];
            }
        }
    }
}

// ============================================================================
// fallback (no workspace): in-kernel gather+window+convert (R1 structure)
// ============================================================================
#define BM 128
#define BN 128
#define BK 32
#define NTILES_N 7
#define NTILES_M 150
#define NWG (NTILES_M * NTILES_N)
#define LDSS 40
__global__ __launch_bounds__(256) void stft_gemm_fb(
    const float* __restrict__ sig, const float* __restrict__ wnd,
    const float* __restrict__ dcos, const float* __restrict__ dsin,
    float* __restrict__ out)
{
    __shared__ ushort As[BM * LDSS];
    __shared__ ushort Bs[BN * LDSS];
    __shared__ int rowBase[BM];

    const int tid = threadIdx.x;
    const int bid = blockIdx.x;
    const int mt  = bid / NTILES_N;
    const int nt  = bid - mt * NTILES_N;
    const int m0  = mt * BM;
    const int j0  = nt * BN;

    if (tid < BM) {
        int m = m0 + tid;
        int v = -1;
        if (m < M_TOTAL) {
            int b  = m / FRAMES;
            int fl = m - b * FRAMES;
            v = b * SIGLEN + fl * FSTEP;
        }
        rowBase[tid] = v;
    }

    const int rS = tid >> 1;
    const int hS = tid & 1;

    const float* bRow = nullptr;
    {
        int j = j0 + rS;
        if (j < NOUT) {
            const float* srcm = (j & 1) ? dsin : dcos;
            bRow = srcm + (size_t)(j >> 1) * K_TOTAL;
        }
    }

    const int lane = tid & 63;
    const int wave = tid >> 6;
    const int wm   = wave >> 1;
    const int wn   = wave & 1;
    const int lr   = lane & 15;
    const int lg   = lane >> 4;

    f32x4 acc[4][4];
    #pragma unroll
    for (int i = 0; i < 4; ++i)
        #pragma unroll
        for (int jj = 0; jj < 4; ++jj)
            acc[i][jj] = (f32x4){0.f, 0.f, 0.f, 0.f};

    __syncthreads();

    for (int k0 = 0; k0 < K_TOTAL; k0 += BK) {
        {
            int base = rowBase[rS];
            float4 f0, f1, f2, f3;
            if (base >= 0) {
                const float4* sp = (const float4*)(sig + base + k0 + hS * 16);
                f0 = sp[0]; f1 = sp[1]; f2 = sp[2]; f3 = sp[3];
            } else {
                f0 = make_float4(0.f,0.f,0.f,0.f); f1 = f0; f2 = f0; f3 = f0;
            }
            const float4* wp = (const float4*)(wnd + k0 + hS * 16);
            float4 w0 = wp[0], w1 = wp[1], w2 = wp[2], w3 = wp[3];
            uint4 p0, p1;
            p0.x = f2bf_pair(f0.x * w0.x, f0.y * w0.y);
            p0.y = f2bf_pair(f0.z * w0.z, f0.w * w0.w);
            p0.z = f2bf_pair(f1.x * w1.x, f1.y * w1.y);
            p0.w = f2bf_pair(f1.z * w1.z, f1.w * w1.w);
            p1.x = f2bf_pair(f2.x * w2.x, f2.y * w2.y);
            p1.y = f2bf_pair(f2.z * w2.z, f2.w * w2.w);
            p1.z = f2bf_pair(f3.x * w3.x, f3.y * w3.y);
            p1.w = f2bf_pair(f3.z * w3.z, f3.w * w3.w);
            uint4* dst = (uint4*)&As[rS * LDSS + hS * 16];
            dst[0] = p0; dst[1] = p1;
        }
        {
            uint4 p0, p1;
            if (bRow) {
                const float4* sp = (const float4*)(bRow + k0 + hS * 16);
                float4 f0 = sp[0], f1 = sp[1], f2 = sp[2], f3 = sp[3];
                p0.x = f2bf_pair(f0.x, f0.y);
                p0.y = f2bf_pair(f0.z, f0.w);
                p0.z = f2bf_pair(f1.x, f1.y);
                p0.w = f2bf_pair(f1.z, f1.w);
                p1.x = f2bf_pair(f2.x, f2.y);
                p1.y = f2bf_pair(f2.z, f2.w);
                p1.z = f2bf_pair(f3.x, f3.y);
                p1.w = f2bf_pair(f3.z, f3.w);
            } else {
                p0 = make_uint4(0u,0u,0u,0u); p1 = p0;
            }
            uint4* dst = (uint4*)&Bs[rS * LDSS + hS * 16];
            dst[0] = p0; dst[1] = p1;
        }
        __syncthreads();

        bf16x8 a[4], b[4];
        #pragma unroll
        for (int i = 0; i < 4; ++i)
            a[i] = *(const bf16x8*)&As[(wm * 64 + i * 16 + lr) * LDSS + lg * 8];
        #pragma unroll
        for (int i = 0; i < 4; ++i)
            b[i] = *(const bf16x8*)&Bs[(wn * 64 + i * 16 + lr) * LDSS + lg * 8];
        #pragma unroll
        for (int i = 0; i < 4; ++i)
            #pragma unroll
            for (int jj = 0; jj < 4; ++jj)
                acc[i][jj] = __builtin_amdgcn_mfma_f32_16x16x32_bf16(a[i], b[jj], acc[i][jj], 0, 0, 0);

        __syncthreads();
    }

    const int mb = m0 + wm * 64;
    const int jb = j0 + wn * 64;
    #pragma unroll
    for (int i = 0; i < 4; ++i) {
        #pragma unroll
        for (int jj = 0; jj < 4; ++jj) {
            int col = jb + jj * 16 + lr;
            if (col >= NOUT) continue;
            #pragma unroll
            for (int r = 0; r < 4; ++r) {
                int row = mb + i * 16 + lg * 4 + r;
                if (row < M_TOTAL)
                    out[(size_t)row * NOUT + col] = acc[i][jj][r];
            }
        }
    }
}

extern "C" void kernel_launch(void* const* d_in, const int* in_sizes, int n_in,
                              void* d_out, int out_size, void* d_ws, size_t ws_size,
                              hipStream_t stream) {
    const float* sig  = (const float*)d_in[0];
    const float* wnd  = (const float*)d_in[1];
    const float* dcos = (const float*)d_in[2];
    const float* dsin = (const float*)d_in[3];
    float* out = (float*)d_out;

    if (ws_size >= WS_NEEDED && d_ws != nullptr) {
        ushort* sbf = (ushort*)d_ws;
        ushort* Bws = sbf + SIG_ELEMS;   // A k-pad overreads land in Bws (finite bf16 x 0)
        prep_all<<<dim3(PREP_SIG_BLOCKS + PREP_B_BLOCKS), dim3(256), 0, stream>>>(
            sig, wnd, dcos, dsin, sbf, Bws);
        stft_gemm_bp<<<dim3(GNWG), dim3(512), 0, stream>>>(sbf, Bws, out);
    } else {
        stft_gemm_fb<<<dim3(NWG), dim3(256), 0, stream>>>(sig, wnd, dcos, dsin, out);
    }
}